// Round 10
// baseline (365.255 us; speedup 1.0000x reference)
//
#include <hip/hip_runtime.h>

// CGConv x2 + masked readout. N=50000, E=800000, C=64.
// R10: DIAGNOSTIC ROUND. Real pipeline = R8 (unchanged, correct). Plus 4
// ablation kernels on the same CSR/tables -> scratch sink, isolating:
//   k_abl_base : binsearch + LDS staging skeleton
//   k_abl_load : Ps random loads + flush skeleton (no math, no vmem in flush)
//   k_abl_math : msg2 math + flush skeleton (NO vmem in loop, synth operands)
//   k_abl_nf   : loads + math, no per-node flush
// Kernel times of these four identify the ~88us invariant's owner.

#define NN 50000
#define EE 800000
#define N2 50176
#define NTILE 782
#define NWAVES 8192
#define EPW 98

typedef short bf16x8 __attribute__((ext_vector_type(8)));
typedef float f32x4 __attribute__((ext_vector_type(4)));
typedef unsigned int uint4v __attribute__((ext_vector_type(4)));
typedef unsigned short u16x4 __attribute__((ext_vector_type(4)));
typedef int int4v __attribute__((ext_vector_type(4)));

#define LN2F 0.6931471805599453f
#define L2EF 1.4426950408889634f

#if __has_builtin(__builtin_amdgcn_exp2f)
#define EXP2(x) __builtin_amdgcn_exp2f(x)
#else
#define EXP2(x) __expf(LN2F * (x))
#endif
#if __has_builtin(__builtin_amdgcn_logf)
#define LOG2(x) __builtin_amdgcn_logf(x)
#else
#define LOG2(x) (L2EF * __logf(x))
#endif
#if __has_builtin(__builtin_amdgcn_rcpf)
#define RCPF(x) __builtin_amdgcn_rcpf(x)
#else
#define RCPF(x) (1.0f / (x))
#endif

__device__ __forceinline__ unsigned short f2b(float f) {
    unsigned int u = __builtin_bit_cast(unsigned int, f);
    return (unsigned short)((u + 0x7fffu + ((u >> 16) & 1u)) >> 16);
}
__device__ __forceinline__ float b2f(unsigned short b) {
    unsigned int u = ((unsigned int)b) << 16;
    return __builtin_bit_cast(float, u);
}
__device__ __forceinline__ float lo16f(unsigned int v) {
    return __builtin_bit_cast(float, v << 16);
}
__device__ __forceinline__ float hi16f(unsigned int v) {
    return __builtin_bit_cast(float, v & 0xFFFF0000u);
}

__device__ __forceinline__ unsigned char f2fp8(float f) {
#if __has_builtin(__builtin_amdgcn_cvt_pk_fp8_f32)
    return (unsigned char)(__builtin_amdgcn_cvt_pk_fp8_f32(f, f, 0, false) & 0xff);
#else
    float a = fabsf(f); if (a > 448.f) a = 448.f;
    int e2; float m = frexpf(a, &e2);
    int E = e2 + 6;
    unsigned char r;
    if (a < 0.001953125f) {
        r = (unsigned char)(a * 512.f + 0.5f);
    } else {
        int mant = (int)(m * 16.f + 0.5f) - 8;
        if (mant == 8) { mant = 0; ++E; }
        if (E > 15) { E = 15; mant = 7; }
        r = (unsigned char)((E << 3) | mant);
    }
    return r | (f < 0.f ? 0x80 : 0);
#endif
}
__device__ __forceinline__ float fp8lo(unsigned int v) {
#if __has_builtin(__builtin_amdgcn_cvt_f32_fp8)
    return __builtin_amdgcn_cvt_f32_fp8(v, 0);
#else
    unsigned b = v & 0xff;
    unsigned s = b >> 7, e = (b >> 3) & 15, mn = b & 7;
    float mag = e ? __builtin_ldexpf(1.f + mn * 0.125f, (int)e - 7)
                  : __builtin_ldexpf((float)mn, -9);
    return s ? -mag : mag;
#endif
}
__device__ __forceinline__ float fp8hi(unsigned int v) {
#if __has_builtin(__builtin_amdgcn_cvt_f32_fp8)
    return __builtin_amdgcn_cvt_f32_fp8(v, 1);
#else
    return fp8lo(v >> 8);
#endif
}

__device__ __forceinline__ float msg2(float nF, float Sp) {
    return RCPF(1.f + EXP2(nF)) * LOG2(1.f + EXP2(Sp));
}

__global__ __launch_bounds__(256) void k_deg_prep(const int* __restrict__ ei, int* __restrict__ deg,
                                                  const float* __restrict__ Wf1, const float* __restrict__ Ws1,
                                                  const float* __restrict__ Wf2, const float* __restrict__ Ws2,
                                                  unsigned short* __restrict__ wt) {
    int e = blockIdx.x * 256 + threadIdx.x;
    if (blockIdx.x < 128) {
        int i = e;
        int layer = i >> 14;
        int j = i & 16383;
        int n = j >> 6, k = j & 63;
        const float* Wf = layer ? Wf2 : Wf1;
        const float* Ws = layer ? Ws2 : Ws1;
        float v;
        if (n < 64)       v = Wf[k * 64 + n];
        else if (n < 128) v = Ws[k * 64 + (n - 64)];
        else if (n < 192) v = Wf[(64 + k) * 64 + (n - 128)];
        else              v = Ws[(64 + k) * 64 + (n - 192)];
        int byte = ((n * 128 + k * 2) ^ ((n & 7) << 4)) + layer * 32768;
        *(unsigned short*)((char*)wt + byte) = f2b(v);
    }
    atomicAdd(&deg[ei[EE + e]], 1);
}

__global__ __launch_bounds__(1024) void k_scan1(const int* __restrict__ deg, int* __restrict__ start,
                                                int* __restrict__ csum) {
    __shared__ int s[1024];
    int t = threadIdx.x;
    int i = blockIdx.x * 1024 + t;
    int v = deg[i];
    s[t] = v; __syncthreads();
    for (int off = 1; off < 1024; off <<= 1) {
        int y = (t >= off) ? s[t - off] : 0; __syncthreads();
        s[t] += y; __syncthreads();
    }
    start[i] = s[t] - v;
    if (t == 1023) csum[blockIdx.x] = s[t];
}

__global__ __launch_bounds__(1024) void k_scan23(int* __restrict__ start, const int* __restrict__ csum,
                                                 int* __restrict__ cursor) {
    __shared__ int red[1024];
    int t = threadIdx.x;
    red[t] = (t < (int)blockIdx.x) ? csum[t] : 0;
    __syncthreads();
    for (int off = 512; off; off >>= 1) {
        if (t < off) red[t] += red[t + off];
        __syncthreads();
    }
    int base = red[0];
    int i = blockIdx.x * 1024 + t;
    int nv = start[i] + base;
    start[i] = nv;
    cursor[i] = nv;
}

__global__ __launch_bounds__(256) void k_fill(const int* __restrict__ ei, int* __restrict__ cursor,
                                              int* __restrict__ esrc) {
    int e = blockIdx.x * 256 + threadIdx.x;
    int dst = ei[EE + e];
    int p = atomicAdd(&cursor[dst], 1);
    esrc[p] = ei[e];
}

template <bool F32IN>
__global__ __launch_bounds__(256) void k_proj(const void* __restrict__ hin,
                                              const unsigned short* __restrict__ wt,
                                              const float* __restrict__ bfv, const float* __restrict__ bsv,
                                              unsigned short* __restrict__ Pd, unsigned char* __restrict__ Ps) {
    __shared__ unsigned short w_s[256 * 64];
    __shared__ unsigned short a_s[64 * 64];
    const int t = threadIdx.x;
    {
        const uint4v* src = (const uint4v*)wt;
        uint4v* dp = (uint4v*)w_s;
        #pragma unroll
        for (int i = 0; i < 8; ++i) dp[t + 256 * i] = src[t + 256 * i];
    }
    const int lane = t & 63, wid = t >> 6;
    const int cbase = lane & 15, q = lane >> 4;
    const int tile = blockIdx.x;

    #pragma unroll
    for (int i = 0; i < 2; ++i) {
        int ch = t + 256 * i;
        int r = ch >> 3, c8 = ch & 7;
        int node = tile * 64 + r;
        u16x4 lo = {0, 0, 0, 0}, hi = {0, 0, 0, 0};
        if (node < NN) {
            if (F32IN) {
                const float* xp = (const float*)hin + node * 64 + c8 * 8;
                f32x4 v0 = *(const f32x4*)xp;
                f32x4 v1 = *(const f32x4*)(xp + 4);
                lo[0] = f2b(v0[0]); lo[1] = f2b(v0[1]); lo[2] = f2b(v0[2]); lo[3] = f2b(v0[3]);
                hi[0] = f2b(v1[0]); hi[1] = f2b(v1[1]); hi[2] = f2b(v1[2]); hi[3] = f2b(v1[3]);
            } else {
                const unsigned short* hp = (const unsigned short*)hin + node * 64 + c8 * 8;
                lo = *(const u16x4*)hp;
                hi = *(const u16x4*)(hp + 4);
            }
        }
        int byte = (r * 128 + c8 * 16) ^ ((r & 7) << 4);
        *(u16x4*)((char*)a_s + byte) = lo;
        *(u16x4*)((char*)a_s + byte + 8) = hi;
    }
    __syncthreads();

    f32x4 acc[4][4];
    #pragma unroll
    for (int m = 0; m < 4; ++m)
        #pragma unroll
        for (int n = 0; n < 4; ++n) acc[m][n] = (f32x4){0.f, 0.f, 0.f, 0.f};

    #pragma unroll
    for (int ks = 0; ks < 2; ++ks) {
        bf16x8 a[4];
        #pragma unroll
        for (int m = 0; m < 4; ++m) {
            int mr = m * 16 + cbase;
            a[m] = *(const bf16x8*)((const char*)a_s + mr * 128 + ((ks * 64 + q * 16) ^ ((mr & 7) << 4)));
        }
        #pragma unroll
        for (int n = 0; n < 4; ++n) {
            int bn = wid * 64 + n * 16 + cbase;
            bf16x8 b = *(const bf16x8*)((const char*)w_s + bn * 128 + ((ks * 64 + q * 16) ^ ((bn & 7) << 4)));
            #pragma unroll
            for (int m = 0; m < 4; ++m)
                acc[m][n] = __builtin_amdgcn_mfma_f32_16x16x32_bf16(a[m], b, acc[m][n], 0, 0, 0);
        }
    }

    #pragma unroll
    for (int n = 0; n < 4; ++n) {
        int col = wid * 64 + n * 16 + cbase;
        if (col < 128) {
            int oidx = (col < 64) ? 2 * col : 2 * (col - 64) + 1;
            float scale = (col < 64) ? -L2EF : L2EF;
            #pragma unroll
            for (int m = 0; m < 4; ++m) {
                int node = tile * 64 + m * 16 + q * 4;
                #pragma unroll
                for (int r = 0; r < 4; ++r)
                    Pd[(node + r) * 128 + oidx] = f2b(acc[m][n][r] * scale);
            }
        } else {
            float bias, scale; int boff;
            if (col < 192) { scale = -L2EF; bias = bfv[col - 128]; boff = 2 * (col - 128); }
            else           { scale =  L2EF; bias = bsv[col - 192]; boff = 2 * (col - 192) + 1; }
            #pragma unroll
            for (int m = 0; m < 4; ++m) {
                int node = tile * 64 + m * 16 + q * 4;
                #pragma unroll
                for (int r = 0; r < 4; ++r)
                    Ps[(node + r) * 128 + boff] = f2fp8((acc[m][n][r] + bias) * scale);
            }
        }
    }
}

// ---- real gather (R8, unchanged) ----
template <int LAYER>
__global__ __launch_bounds__(256) void k_gather(const unsigned int* __restrict__ Pd,
                                                const unsigned short* __restrict__ Ps,
                                                const int* __restrict__ esrc, const int* __restrict__ start,
                                                const float* __restrict__ x,
                                                unsigned short* __restrict__ h1b,
                                                const float* __restrict__ surf, const float* __restrict__ Wlin,
                                                float* __restrict__ scal) {
    __shared__ int idx_s[4][256];
    __shared__ int end_s[4][136];
    const int lane = threadIdx.x & 63;
    const int wid = threadIdx.x >> 6;
    const int w = blockIdx.x * 4 + wid;

    int t0 = w * EPW, t1 = t0 + EPW;
    int lo = 0, hi = NN;
    while (lo < hi) { int mid = (lo + hi) >> 1; if (start[mid] < t0) lo = mid + 1; else hi = mid; }
    const int n0 = lo;
    hi = NN;
    while (lo < hi) { int mid = (lo + hi) >> 1; if (start[mid] < t1) lo = mid + 1; else hi = mid; }
    const int n1 = lo;
    const int nn = n1 - n0;

    const int e0 = __builtin_amdgcn_readfirstlane(start[n0]);
    const int cnt = __builtin_amdgcn_readfirstlane(start[n1]) - e0;
    int* idxp = idx_s[wid];
    for (int k = lane; k < cnt + 24; k += 64)
        idxp[k] = (k < cnt) ? esrc[e0 + k] : 0;
    int* endp = end_s[wid];
    for (int k = lane; k < 136; k += 64)
        endp[k] = (k < nn && k < 135) ? (start[n0 + 1 + k] - e0) : 0x7fffffff;

    float wlin = (LAYER == 2) ? Wlin[lane] : 0.f;
    float so = 0.f, ssum = 0.f;

    int n = n0;
    int nend = 0x7fffffff;
    float acc = 0.f, nfd = 0.f, sd = 0.f, xf = 0.f;
    unsigned int dv1 = 0, dv2 = 0;
    float xf1 = 0.f, xf2 = 0.f;
    if (nn > 0) {
        unsigned int dv0 = Pd[n0 * 64 + lane];
        nfd = lo16f(dv0); sd = hi16f(dv0);
        xf = (LAYER == 1) ? x[n0 * 64 + lane] : b2f(h1b[n0 * 64 + lane]);
        int p1 = (n0 + 1 < NN) ? n0 + 1 : NN - 1;
        int p2 = (n0 + 2 < NN) ? n0 + 2 : NN - 1;
        dv1 = Pd[p1 * 64 + lane];
        xf1 = (LAYER == 1) ? x[p1 * 64 + lane] : b2f(h1b[p1 * 64 + lane]);
        dv2 = Pd[p2 * 64 + lane];
        xf2 = (LAYER == 1) ? x[p2 * 64 + lane] : b2f(h1b[p2 * 64 + lane]);
        nend = endp[0];
    }

#define FLUSH() do {                                                          \
    if (LAYER == 1) {                                                         \
        h1b[n * 64 + lane] = f2b(xf + LN2F * acc);                            \
    } else {                                                                  \
        float v_ = (xf + LN2F * acc) * wlin;                                  \
        _Pragma("unroll")                                                     \
        for (int off_ = 32; off_; off_ >>= 1) v_ += __shfl_xor(v_, off_);     \
        if (lane == 0) { so += v_ * surf[n]; ssum += surf[n]; }               \
    }                                                                         \
    ++n; acc = 0.f;                                                           \
    nfd = lo16f(dv1); sd = hi16f(dv1); xf = xf1;                              \
    dv1 = dv2; xf1 = xf2;                                                     \
    { int np_ = (n + 2 < NN) ? n + 2 : NN - 1;                                \
      dv2 = Pd[np_ * 64 + lane];                                              \
      xf2 = (LAYER == 1) ? x[np_ * 64 + lane] : b2f(h1b[np_ * 64 + lane]); }  \
    { int ii_ = n - n0;                                                       \
      nend = (ii_ < 135) ? endp[ii_]                                          \
                         : (__builtin_amdgcn_readfirstlane(start[n + 1]) - e0); } \
} while (0)

#define LOADB(vv, kb_) do {                                                   \
    int4v j0_ = *(const int4v*)(idxp + (kb_));                                \
    int4v j1_ = *(const int4v*)(idxp + (kb_) + 4);                            \
    vv[0] = Ps[j0_[0] * 64 + lane]; vv[1] = Ps[j0_[1] * 64 + lane];           \
    vv[2] = Ps[j0_[2] * 64 + lane]; vv[3] = Ps[j0_[3] * 64 + lane];           \
    vv[4] = Ps[j1_[0] * 64 + lane]; vv[5] = Ps[j1_[1] * 64 + lane];           \
    vv[6] = Ps[j1_[2] * 64 + lane]; vv[7] = Ps[j1_[3] * 64 + lane];           \
} while (0)

#define COMP(vv, kb_) do {                                                    \
    _Pragma("unroll")                                                         \
    for (int i_ = 0; i_ < 8; ++i_) {                                          \
        int k_ = (kb_) + i_;                                                  \
        while (k_ == nend && n < n1) FLUSH();                                 \
        float m_ = msg2(nfd + fp8lo(vv[i_]), sd + fp8hi(vv[i_]));             \
        if (k_ < cnt) acc += m_;                                              \
    }                                                                         \
} while (0)

    if (cnt > 0) {
        unsigned int vA[8], vB[8];
        LOADB(vA, 0);
        int kb = 0;
        while (true) {
            LOADB(vB, kb + 8);
            COMP(vA, kb);
            kb += 8; if (kb >= cnt) break;
            LOADB(vA, kb + 8);
            COMP(vB, kb);
            kb += 8; if (kb >= cnt) break;
        }
    }
    while (n < n1) FLUSH();

#undef FLUSH
#undef LOADB
#undef COMP

    if (LAYER == 2) {
        __shared__ float ps[8];
        if (lane == 0) { ps[wid] = so; ps[4 + wid] = ssum; }
        __syncthreads();
        if (threadIdx.x == 0) {
            atomicAdd(scal + 0, ps[0] + ps[1] + ps[2] + ps[3]);
            atomicAdd(scal + 1, ps[4] + ps[5] + ps[6] + ps[7]);
        }
    }
}

// ---- ablation body ----
// MODE 1: Ps loads + flush skeleton, no math, no vmem in flush.
// MODE 2: msg2 math + flush skeleton, NO vmem in loop (synthesized operands).
// MODE 3: Ps loads + msg2, no per-node flush.
// MODE 4: binsearch + staging only.
__device__ __forceinline__ unsigned int synthv(int j) {
    return (((unsigned int)j * 2654435761u) & 0x00ff00ffu) | 0x3f003f00u;
}

template <int MODE>
__device__ __forceinline__ void abl_body(const unsigned int* __restrict__ Pd,
                                         const unsigned short* __restrict__ Ps,
                                         const int* __restrict__ esrc,
                                         const int* __restrict__ start,
                                         unsigned short* __restrict__ sink) {
    __shared__ int idx_s[4][256];
    __shared__ int end_s[4][136];
    const int lane = threadIdx.x & 63;
    const int wid = threadIdx.x >> 6;
    const int w = blockIdx.x * 4 + wid;

    int t0 = w * EPW, t1 = t0 + EPW;
    int lo = 0, hi = NN;
    while (lo < hi) { int mid = (lo + hi) >> 1; if (start[mid] < t0) lo = mid + 1; else hi = mid; }
    const int n0 = lo;
    hi = NN;
    while (lo < hi) { int mid = (lo + hi) >> 1; if (start[mid] < t1) lo = mid + 1; else hi = mid; }
    const int n1 = lo;
    const int nn = n1 - n0;

    const int e0 = __builtin_amdgcn_readfirstlane(start[n0]);
    const int cnt = __builtin_amdgcn_readfirstlane(start[n1]) - e0;
    int* idxp = idx_s[wid];
    for (int k = lane; k < cnt + 24; k += 64)
        idxp[k] = (k < cnt) ? esrc[e0 + k] : 0;
    int* endp = end_s[wid];
    for (int k = lane; k < 136; k += 64)
        endp[k] = (k < nn && k < 135) ? (start[n0 + 1 + k] - e0) : 0x7fffffff;

    if (MODE == 4) {
        sink[w * 64 + lane] = f2b((float)(idxp[lane] + endp[lane & 63]));
        return;
    }

    int n = n0;
    int nend = (nn > 0) ? endp[0] : 0x7fffffff;
    float acc = 0.f;
    unsigned int uacc = 0;
    float nfd = 0.5f, sd = 0.5f;
    unsigned int dv1 = 0, dv2 = 0;
    if (nn > 0 && MODE == 2) {
        unsigned h0 = synthv(n0);
        nfd = lo16f(h0); sd = hi16f(h0);
        dv1 = synthv(n0 + 1); dv2 = synthv(n0 + 2);
    } else if (nn > 0 && MODE == 3) {
        unsigned int dv0 = Pd[n0 * 64 + lane];
        nfd = lo16f(dv0); sd = hi16f(dv0);
    }

#define AFLUSH() do {                                                         \
    sink[n * 64 + lane] = (MODE == 1) ? (unsigned short)(uacc & 0xffff)       \
                                      : f2b(acc);                             \
    ++n; acc = 0.f; uacc = 0;                                                 \
    if (MODE == 2) {                                                          \
        nfd = lo16f(dv1); sd = hi16f(dv1);                                    \
        dv1 = dv2; dv2 = synthv(n + 2);                                       \
    }                                                                         \
    { int ii_ = n - n0;                                                       \
      nend = (ii_ < 135) ? endp[ii_] : 0x7fffffff; }                          \
} while (0)

#define ALOADB(vv, kb_) do {                                                  \
    int4v j0_ = *(const int4v*)(idxp + (kb_));                                \
    int4v j1_ = *(const int4v*)(idxp + (kb_) + 4);                            \
    if (MODE == 2) {                                                          \
        vv[0] = synthv(j0_[0]); vv[1] = synthv(j0_[1]);                       \
        vv[2] = synthv(j0_[2]); vv[3] = synthv(j0_[3]);                       \
        vv[4] = synthv(j1_[0]); vv[5] = synthv(j1_[1]);                       \
        vv[6] = synthv(j1_[2]); vv[7] = synthv(j1_[3]);                       \
    } else {                                                                  \
        vv[0] = Ps[j0_[0] * 64 + lane]; vv[1] = Ps[j0_[1] * 64 + lane];       \
        vv[2] = Ps[j0_[2] * 64 + lane]; vv[3] = Ps[j0_[3] * 64 + lane];       \
        vv[4] = Ps[j1_[0] * 64 + lane]; vv[5] = Ps[j1_[1] * 64 + lane];       \
        vv[6] = Ps[j1_[2] * 64 + lane]; vv[7] = Ps[j1_[3] * 64 + lane];       \
    }                                                                         \
} while (0)

#define ACOMP(vv, kb_) do {                                                   \
    _Pragma("unroll")                                                         \
    for (int i_ = 0; i_ < 8; ++i_) {                                          \
        int k_ = (kb_) + i_;                                                  \
        if (MODE != 3) { while (k_ == nend && n < n1) AFLUSH(); }             \
        if (MODE == 1) { if (k_ < cnt) uacc += vv[i_]; }                      \
        else { float m_ = msg2(nfd + fp8lo(vv[i_]), sd + fp8hi(vv[i_]));      \
               if (k_ < cnt) acc += m_; }                                     \
    }                                                                         \
} while (0)

    if (cnt > 0) {
        unsigned int vA[8], vB[8];
        ALOADB(vA, 0);
        int kb = 0;
        while (true) {
            ALOADB(vB, kb + 8);
            ACOMP(vA, kb);
            kb += 8; if (kb >= cnt) break;
            ALOADB(vA, kb + 8);
            ACOMP(vB, kb);
            kb += 8; if (kb >= cnt) break;
        }
    }
    if (MODE == 3) {
        sink[w * 64 + lane] = f2b(acc);
    } else {
        while (n < n1) AFLUSH();
    }
#undef AFLUSH
#undef ALOADB
#undef ACOMP
}

__global__ __launch_bounds__(256) void k_abl_load(const unsigned int* __restrict__ Pd,
                                                  const unsigned short* __restrict__ Ps,
                                                  const int* __restrict__ esrc,
                                                  const int* __restrict__ start,
                                                  unsigned short* __restrict__ sink) {
    abl_body<1>(Pd, Ps, esrc, start, sink);
}
__global__ __launch_bounds__(256) void k_abl_math(const unsigned int* __restrict__ Pd,
                                                  const unsigned short* __restrict__ Ps,
                                                  const int* __restrict__ esrc,
                                                  const int* __restrict__ start,
                                                  unsigned short* __restrict__ sink) {
    abl_body<2>(Pd, Ps, esrc, start, sink);
}
__global__ __launch_bounds__(256) void k_abl_nf(const unsigned int* __restrict__ Pd,
                                                const unsigned short* __restrict__ Ps,
                                                const int* __restrict__ esrc,
                                                const int* __restrict__ start,
                                                unsigned short* __restrict__ sink) {
    abl_body<3>(Pd, Ps, esrc, start, sink);
}
__global__ __launch_bounds__(256) void k_abl_base(const unsigned int* __restrict__ Pd,
                                                  const unsigned short* __restrict__ Ps,
                                                  const int* __restrict__ esrc,
                                                  const int* __restrict__ start,
                                                  unsigned short* __restrict__ sink) {
    abl_body<4>(Pd, Ps, esrc, start, sink);
}

__global__ void k_final(const float* __restrict__ scal, const float* __restrict__ blin,
                        float* __restrict__ out) {
    out[0] = (scal[0] + (float)NN * blin[0]) / scal[1];
}

extern "C" void kernel_launch(void* const* d_in, const int* in_sizes, int n_in,
                              void* d_out, int out_size, void* d_ws, size_t ws_size,
                              hipStream_t stream) {
    const float* x    = (const float*)d_in[0];
    const int*   ei   = (const int*)d_in[1];
    const float* surf = (const float*)d_in[2];
    const float* Wf1  = (const float*)d_in[3];
    const float* bf1  = (const float*)d_in[4];
    const float* Ws1  = (const float*)d_in[5];
    const float* bs1  = (const float*)d_in[6];
    const float* Wf2  = (const float*)d_in[7];
    const float* bf2  = (const float*)d_in[8];
    const float* Ws2  = (const float*)d_in[9];
    const float* bs2  = (const float*)d_in[10];
    const float* Wlin = (const float*)d_in[11];
    const float* blin = (const float*)d_in[12];

    unsigned char* ws = (unsigned char*)d_ws;
    int* deg    = (int*)(ws);                      // 200704
    int* csum   = (int*)(ws + 200704);             // 256
    float* scal = (float*)(ws + 200960);           // 64
    int* start  = (int*)(ws + 201024);             // 200704
    int* cursor = (int*)(ws + 401728);             // 200704
    int* esrc   = (int*)(ws + 602432);             // 3,200,000
    unsigned short* h1b = (unsigned short*)(ws + 3802432);   // 6,406,144
    unsigned short* Pd  = (unsigned short*)(ws + 10208576);  // 12,812,288
    unsigned char*  Ps  = (unsigned char*)(ws + 23020864);   // 6,406,144 (fp8)
    unsigned short* wt  = (unsigned short*)(ws + 35833152);  // 65,536
    unsigned short* sink = (unsigned short*)(ws + 35898688); // 6,406,144 scratch

    hipMemsetAsync(d_ws, 0, 201024, stream);

    k_deg_prep<<<3125, 256, 0, stream>>>(ei, deg, Wf1, Ws1, Wf2, Ws2, wt);
    k_scan1<<<49, 1024, 0, stream>>>(deg, start, csum);
    k_scan23<<<49, 1024, 0, stream>>>(start, csum, cursor);
    k_fill<<<3125, 256, 0, stream>>>(ei, cursor, esrc);

    k_proj<true><<<NTILE, 256, 0, stream>>>(x, wt, bf1, bs1, Pd, Ps);
    k_gather<1><<<2048, 256, 0, stream>>>((const unsigned int*)Pd, (const unsigned short*)Ps,
                                          esrc, start, x, h1b, surf, Wlin, scal);
    k_proj<false><<<NTILE, 256, 0, stream>>>(h1b, wt + 16384, bf2, bs2, Pd, Ps);
    k_gather<2><<<2048, 256, 0, stream>>>((const unsigned int*)Pd, (const unsigned short*)Ps,
                                          esrc, start, x, h1b, surf, Wlin, scal);
    k_final<<<1, 1, 0, stream>>>(scal, blin, (float*)d_out);

    // diagnostics (write only to sink scratch; deterministic; after k_final)
    k_abl_base<<<2048, 256, 0, stream>>>((const unsigned int*)Pd, (const unsigned short*)Ps,
                                         esrc, start, sink);
    k_abl_load<<<2048, 256, 0, stream>>>((const unsigned int*)Pd, (const unsigned short*)Ps,
                                         esrc, start, sink);
    k_abl_math<<<2048, 256, 0, stream>>>((const unsigned int*)Pd, (const unsigned short*)Ps,
                                         esrc, start, sink);
    k_abl_nf<<<2048, 256, 0, stream>>>((const unsigned int*)Pd, (const unsigned short*)Ps,
                                       esrc, start, sink);
}

// Round 11
// 300.631 us; speedup vs baseline: 1.2150x; 1.2150x over previous
//
#include <hip/hip_runtime.h>

// CGConv x2 + masked readout. N=50000, E=800000, C=64.
// R11: ALL-LEAN gather passes. R10 diagnostics showed the 86us invariant was
// the heavy per-node FLUSH (3 vmem streams + readout interleaved into the Ps
// pipeline ~50k times), not loads/math/bytes (R9 passA with lean flush = ~17us
// per 400k edges). Structure: split CSR by src-half (L2-fit windows), 4 lean
// gather passes (flush = bf16 agg store + Pd prefetch ONLY), residual/readout
// in separate streaming kernels.
//
// ws: deg(401408) csum(512) scal(64) start(401408) cursor(401408) esrc(3.2M)
//     h1b(6.4M) Pd(12.8M) Ps(6.4M fp8) aggA(6.4M) aggB(6.4M) wt(64K)

#define NN 50000
#define EE 800000
#define HH 25000          // src split point
#define N2 50176          // 49*1024
#define NTILE 782
#define NWAVES 8192

typedef short bf16x8 __attribute__((ext_vector_type(8)));
typedef float f32x4 __attribute__((ext_vector_type(4)));
typedef unsigned int uint4v __attribute__((ext_vector_type(4)));
typedef unsigned short u16x4 __attribute__((ext_vector_type(4)));
typedef int int4v __attribute__((ext_vector_type(4)));

#define LN2F 0.6931471805599453f
#define L2EF 1.4426950408889634f

#if __has_builtin(__builtin_amdgcn_exp2f)
#define EXP2(x) __builtin_amdgcn_exp2f(x)
#else
#define EXP2(x) __expf(LN2F * (x))
#endif
#if __has_builtin(__builtin_amdgcn_logf)
#define LOG2(x) __builtin_amdgcn_logf(x)
#else
#define LOG2(x) (L2EF * __logf(x))
#endif
#if __has_builtin(__builtin_amdgcn_rcpf)
#define RCPF(x) __builtin_amdgcn_rcpf(x)
#else
#define RCPF(x) (1.0f / (x))
#endif

__device__ __forceinline__ unsigned short f2b(float f) {
    unsigned int u = __builtin_bit_cast(unsigned int, f);
    return (unsigned short)((u + 0x7fffu + ((u >> 16) & 1u)) >> 16);
}
__device__ __forceinline__ float b2f(unsigned short b) {
    unsigned int u = ((unsigned int)b) << 16;
    return __builtin_bit_cast(float, u);
}
__device__ __forceinline__ float lo16f(unsigned int v) {
    return __builtin_bit_cast(float, v << 16);
}
__device__ __forceinline__ float hi16f(unsigned int v) {
    return __builtin_bit_cast(float, v & 0xFFFF0000u);
}

__device__ __forceinline__ unsigned char f2fp8(float f) {
#if __has_builtin(__builtin_amdgcn_cvt_pk_fp8_f32)
    return (unsigned char)(__builtin_amdgcn_cvt_pk_fp8_f32(f, f, 0, false) & 0xff);
#else
    float a = fabsf(f); if (a > 448.f) a = 448.f;
    int e2; float m = frexpf(a, &e2);
    int E = e2 + 6;
    unsigned char r;
    if (a < 0.001953125f) {
        r = (unsigned char)(a * 512.f + 0.5f);
    } else {
        int mant = (int)(m * 16.f + 0.5f) - 8;
        if (mant == 8) { mant = 0; ++E; }
        if (E > 15) { E = 15; mant = 7; }
        r = (unsigned char)((E << 3) | mant);
    }
    return r | (f < 0.f ? 0x80 : 0);
#endif
}
__device__ __forceinline__ float fp8lo(unsigned int v) {
#if __has_builtin(__builtin_amdgcn_cvt_f32_fp8)
    return __builtin_amdgcn_cvt_f32_fp8(v, 0);
#else
    unsigned b = v & 0xff;
    unsigned s = b >> 7, e = (b >> 3) & 15, mn = b & 7;
    float mag = e ? __builtin_ldexpf(1.f + mn * 0.125f, (int)e - 7)
                  : __builtin_ldexpf((float)mn, -9);
    return s ? -mag : mag;
#endif
}
__device__ __forceinline__ float fp8hi(unsigned int v) {
#if __has_builtin(__builtin_amdgcn_cvt_f32_fp8)
    return __builtin_amdgcn_cvt_f32_fp8(v, 1);
#else
    return fp8lo(v >> 8);
#endif
}

// per-edge message / ln2, pre-scaled: nF = -log2e*F, Sp = log2e*S
__device__ __forceinline__ float msg2(float nF, float Sp) {
    return RCPF(1.f + EXP2(nF)) * LOG2(1.f + EXP2(Sp));
}

// deg count (virtual nodes: dst + (src<HH ? 0 : N2)) + (blocks 0..127) W prep.
__global__ __launch_bounds__(256) void k_deg_prep(const int* __restrict__ ei, int* __restrict__ deg,
                                                  const float* __restrict__ Wf1, const float* __restrict__ Ws1,
                                                  const float* __restrict__ Wf2, const float* __restrict__ Ws2,
                                                  unsigned short* __restrict__ wt) {
    int e = blockIdx.x * 256 + threadIdx.x;
    if (blockIdx.x < 128) {
        int i = e;
        int layer = i >> 14;
        int j = i & 16383;
        int n = j >> 6, k = j & 63;
        const float* Wf = layer ? Wf2 : Wf1;
        const float* Ws = layer ? Ws2 : Ws1;
        float v;
        if (n < 64)       v = Wf[k * 64 + n];
        else if (n < 128) v = Ws[k * 64 + (n - 64)];
        else if (n < 192) v = Wf[(64 + k) * 64 + (n - 128)];
        else              v = Ws[(64 + k) * 64 + (n - 192)];
        int byte = ((n * 128 + k * 2) ^ ((n & 7) << 4)) + layer * 32768;
        *(unsigned short*)((char*)wt + byte) = f2b(v);
    }
    int src = ei[e], dst = ei[EE + e];
    int vn = dst + (src < HH ? 0 : N2);
    atomicAdd(&deg[vn], 1);
}

__global__ __launch_bounds__(1024) void k_scan1(const int* __restrict__ deg, int* __restrict__ start,
                                                int* __restrict__ csum) {
    __shared__ int s[1024];
    int t = threadIdx.x;
    int i = blockIdx.x * 1024 + t;
    int v = deg[i];
    s[t] = v; __syncthreads();
    for (int off = 1; off < 1024; off <<= 1) {
        int y = (t >= off) ? s[t - off] : 0; __syncthreads();
        s[t] += y; __syncthreads();
    }
    start[i] = s[t] - v;
    if (t == 1023) csum[blockIdx.x] = s[t];
}

__global__ __launch_bounds__(1024) void k_scan23(int* __restrict__ start, const int* __restrict__ csum,
                                                 int* __restrict__ cursor) {
    __shared__ int red[1024];
    int t = threadIdx.x;
    red[t] = (t < (int)blockIdx.x) ? csum[t] : 0;
    __syncthreads();
    for (int off = 512; off; off >>= 1) {
        if (t < off) red[t] += red[t + off];
        __syncthreads();
    }
    int base = red[0];
    int i = blockIdx.x * 1024 + t;
    int nv = start[i] + base;
    start[i] = nv;
    cursor[i] = nv;
}

__global__ __launch_bounds__(256) void k_fill(const int* __restrict__ ei, int* __restrict__ cursor,
                                              int* __restrict__ esrc) {
    int e = blockIdx.x * 256 + threadIdx.x;
    int src = ei[e], dst = ei[EE + e];
    int vn = dst + (src < HH ? 0 : N2);
    int p = atomicAdd(&cursor[vn], 1);
    esrc[p] = src;
}

// P = H @ Wcat, 64 nodes x 256 cols per block, 4 waves.
// Pd (per node, 64 dwords): [ -log2e*F_c (lo16 bf16) | log2e*S_c (hi16 bf16) ].
// Ps (per node, 64 ushorts): [ fp8(-log2e*(F_c+bf)) | fp8(log2e*(S_c+bs)) ].
template <bool F32IN>
__global__ __launch_bounds__(256) void k_proj(const void* __restrict__ hin,
                                              const unsigned short* __restrict__ wt,
                                              const float* __restrict__ bfv, const float* __restrict__ bsv,
                                              unsigned short* __restrict__ Pd, unsigned char* __restrict__ Ps) {
    __shared__ unsigned short w_s[256 * 64];
    __shared__ unsigned short a_s[64 * 64];
    const int t = threadIdx.x;
    {
        const uint4v* src = (const uint4v*)wt;
        uint4v* dp = (uint4v*)w_s;
        #pragma unroll
        for (int i = 0; i < 8; ++i) dp[t + 256 * i] = src[t + 256 * i];
    }
    const int lane = t & 63, wid = t >> 6;
    const int cbase = lane & 15, q = lane >> 4;
    const int tile = blockIdx.x;

    #pragma unroll
    for (int i = 0; i < 2; ++i) {
        int ch = t + 256 * i;
        int r = ch >> 3, c8 = ch & 7;
        int node = tile * 64 + r;
        u16x4 lo = {0, 0, 0, 0}, hi = {0, 0, 0, 0};
        if (node < NN) {
            if (F32IN) {
                const float* xp = (const float*)hin + node * 64 + c8 * 8;
                f32x4 v0 = *(const f32x4*)xp;
                f32x4 v1 = *(const f32x4*)(xp + 4);
                lo[0] = f2b(v0[0]); lo[1] = f2b(v0[1]); lo[2] = f2b(v0[2]); lo[3] = f2b(v0[3]);
                hi[0] = f2b(v1[0]); hi[1] = f2b(v1[1]); hi[2] = f2b(v1[2]); hi[3] = f2b(v1[3]);
            } else {
                const unsigned short* hp = (const unsigned short*)hin + node * 64 + c8 * 8;
                lo = *(const u16x4*)hp;
                hi = *(const u16x4*)(hp + 4);
            }
        }
        int byte = (r * 128 + c8 * 16) ^ ((r & 7) << 4);
        *(u16x4*)((char*)a_s + byte) = lo;
        *(u16x4*)((char*)a_s + byte + 8) = hi;
    }
    __syncthreads();

    f32x4 acc[4][4];
    #pragma unroll
    for (int m = 0; m < 4; ++m)
        #pragma unroll
        for (int n = 0; n < 4; ++n) acc[m][n] = (f32x4){0.f, 0.f, 0.f, 0.f};

    #pragma unroll
    for (int ks = 0; ks < 2; ++ks) {
        bf16x8 a[4];
        #pragma unroll
        for (int m = 0; m < 4; ++m) {
            int mr = m * 16 + cbase;
            a[m] = *(const bf16x8*)((const char*)a_s + mr * 128 + ((ks * 64 + q * 16) ^ ((mr & 7) << 4)));
        }
        #pragma unroll
        for (int n = 0; n < 4; ++n) {
            int bn = wid * 64 + n * 16 + cbase;
            bf16x8 b = *(const bf16x8*)((const char*)w_s + bn * 128 + ((ks * 64 + q * 16) ^ ((bn & 7) << 4)));
            #pragma unroll
            for (int m = 0; m < 4; ++m)
                acc[m][n] = __builtin_amdgcn_mfma_f32_16x16x32_bf16(a[m], b, acc[m][n], 0, 0, 0);
        }
    }

    #pragma unroll
    for (int n = 0; n < 4; ++n) {
        int col = wid * 64 + n * 16 + cbase;
        if (col < 128) {
            int oidx = (col < 64) ? 2 * col : 2 * (col - 64) + 1;
            float scale = (col < 64) ? -L2EF : L2EF;
            #pragma unroll
            for (int m = 0; m < 4; ++m) {
                int node = tile * 64 + m * 16 + q * 4;
                #pragma unroll
                for (int r = 0; r < 4; ++r)
                    Pd[(node + r) * 128 + oidx] = f2b(acc[m][n][r] * scale);
            }
        } else {
            float bias, scale; int boff;
            if (col < 192) { scale = -L2EF; bias = bfv[col - 128]; boff = 2 * (col - 128); }
            else           { scale =  L2EF; bias = bsv[col - 192]; boff = 2 * (col - 192) + 1; }
            #pragma unroll
            for (int m = 0; m < 4; ++m) {
                int node = tile * 64 + m * 16 + q * 4;
                #pragma unroll
                for (int r = 0; r < 4; ++r)
                    Ps[(node + r) * 128 + boff] = f2fp8((acc[m][n][r] + bias) * scale);
            }
        }
    }
}

// LEAN gather pass (proven R9-passA shape): flush = bf16 agg store + Pd
// prefetch ONLY. HALF selects the virtual-node range / edge window.
template <int HALF>
__global__ __launch_bounds__(256) void k_glean(const unsigned int* __restrict__ Pd,
                                               const unsigned short* __restrict__ Ps,
                                               const int* __restrict__ esrc, const int* __restrict__ start,
                                               unsigned short* __restrict__ agg) {
    __shared__ int idx_s[4][144];
    __shared__ int end_s[4][80];
    const int lane = threadIdx.x & 63;
    const int wid = threadIdx.x >> 6;
    const int w = blockIdx.x * 4 + wid;
    const int nodeBase = HALF ? N2 : 0;

    const int cntA = start[N2];
    const int eLo = HALF ? cntA : 0;
    const int eHi = HALF ? EE : cntA;
    const int total = eHi - eLo;
    int t0 = eLo + (int)(((long)w * total) / NWAVES);
    int t1 = eLo + (int)(((long)(w + 1) * total) / NWAVES);

    int lo = nodeBase, hi = nodeBase + NN;
    while (lo < hi) { int mid = (lo + hi) >> 1; if (start[mid] < t0) lo = mid + 1; else hi = mid; }
    const int n0 = lo;
    hi = nodeBase + NN;
    while (lo < hi) { int mid = (lo + hi) >> 1; if (start[mid] < t1) lo = mid + 1; else hi = mid; }
    const int n1 = lo;
    const int nn = n1 - n0;

    const int e0 = __builtin_amdgcn_readfirstlane(start[n0]);
    const int cnt = __builtin_amdgcn_readfirstlane(start[n1]) - e0;
    int* idxp = idx_s[wid];
    for (int k = lane; k < cnt + 16; k += 64)
        idxp[k] = (k < cnt) ? esrc[e0 + k] : 0;
    int* endp = end_s[wid];
    for (int k = lane; k < 80; k += 64)
        endp[k] = (k < nn && k < 79) ? (start[n0 + 1 + k] - e0) : 0x7fffffff;

    int n = n0;
    int nend = 0x7fffffff;
    float acc = 0.f, nfd = 0.f, sd = 0.f;
    unsigned int dv1 = 0, dv2 = 0;
    if (nn > 0) {
        int pn0 = n0 - nodeBase;
        unsigned int dv0 = Pd[pn0 * 64 + lane];
        nfd = lo16f(dv0); sd = hi16f(dv0);
        int p1 = (pn0 + 1 < NN) ? pn0 + 1 : NN - 1;
        int p2 = (pn0 + 2 < NN) ? pn0 + 2 : NN - 1;
        dv1 = Pd[p1 * 64 + lane];
        dv2 = Pd[p2 * 64 + lane];
        nend = endp[0];
    }

#define FLUSH() do {                                                          \
    agg[(n - nodeBase) * 64 + lane] = f2b(acc);                               \
    ++n; acc = 0.f;                                                           \
    nfd = lo16f(dv1); sd = hi16f(dv1);                                        \
    dv1 = dv2;                                                                \
    { int np_ = n - nodeBase + 2; if (np_ >= NN) np_ = NN - 1;                \
      dv2 = Pd[np_ * 64 + lane]; }                                            \
    { int ii_ = n - n0;                                                       \
      nend = (ii_ < 79) ? endp[ii_]                                           \
                        : (__builtin_amdgcn_readfirstlane(start[n + 1]) - e0); } \
} while (0)

#define LOADB(vv, kb_) do {                                                   \
    int4v j0_ = *(const int4v*)(idxp + (kb_));                                \
    int4v j1_ = *(const int4v*)(idxp + (kb_) + 4);                            \
    vv[0] = Ps[j0_[0] * 64 + lane]; vv[1] = Ps[j0_[1] * 64 + lane];           \
    vv[2] = Ps[j0_[2] * 64 + lane]; vv[3] = Ps[j0_[3] * 64 + lane];           \
    vv[4] = Ps[j1_[0] * 64 + lane]; vv[5] = Ps[j1_[1] * 64 + lane];           \
    vv[6] = Ps[j1_[2] * 64 + lane]; vv[7] = Ps[j1_[3] * 64 + lane];           \
} while (0)

#define COMP(vv, kb_) do {                                                    \
    _Pragma("unroll")                                                         \
    for (int i_ = 0; i_ < 8; ++i_) {                                          \
        int k_ = (kb_) + i_;                                                  \
        while (k_ == nend && n < n1) FLUSH();                                 \
        float m_ = msg2(nfd + fp8lo(vv[i_]), sd + fp8hi(vv[i_]));             \
        if (k_ < cnt) acc += m_;                                              \
    }                                                                         \
} while (0)

    if (cnt > 0) {
        unsigned int vA[8], vB[8];
        LOADB(vA, 0);
        int kb = 0;
        while (true) {
            LOADB(vB, kb + 8);
            COMP(vA, kb);
            kb += 8; if (kb >= cnt) break;
            LOADB(vA, kb + 8);
            COMP(vB, kb);
            kb += 8; if (kb >= cnt) break;
        }
    }
    while (n < n1) FLUSH();
#undef FLUSH
#undef LOADB
#undef COMP
}

// h1 = x + ln2*(aggA+aggB), streamed, vectorized.
__global__ __launch_bounds__(256) void k_post1(const float* __restrict__ x,
                                               const unsigned short* __restrict__ aggA,
                                               const unsigned short* __restrict__ aggB,
                                               unsigned short* __restrict__ h1b) {
    int i = (blockIdx.x * 256 + threadIdx.x) * 4;
    f32x4 xv = *(const f32x4*)(x + i);
    u16x4 a = *(const u16x4*)(aggA + i);
    u16x4 b = *(const u16x4*)(aggB + i);
    u16x4 o;
    #pragma unroll
    for (int j = 0; j < 4; ++j)
        o[j] = f2b(xv[j] + LN2F * (b2f(a[j]) + b2f(b[j])));
    *(u16x4*)(h1b + i) = o;
}

// readout: h2 = h1 + ln2*(aggA+aggB); so += surf * (h2 . Wlin); ss += surf.
__global__ __launch_bounds__(256) void k_post2(const unsigned short* __restrict__ h1b,
                                               const unsigned short* __restrict__ aggA,
                                               const unsigned short* __restrict__ aggB,
                                               const float* __restrict__ surf, const float* __restrict__ Wlin,
                                               float* __restrict__ scal) {
    const int lane = threadIdx.x & 63, wid = threadIdx.x >> 6;
    float wl = Wlin[lane];
    float so = 0.f, ss = 0.f;
    for (int n = blockIdx.x * 4 + wid; n < NN; n += gridDim.x * 4) {
        int i = n * 64 + lane;
        float h2 = b2f(h1b[i]) + LN2F * (b2f(aggA[i]) + b2f(aggB[i]));
        float v = h2 * wl;
        #pragma unroll
        for (int off = 32; off; off >>= 1) v += __shfl_xor(v, off);
        if (lane == 0) { so += v * surf[n]; ss += surf[n]; }
    }
    __shared__ float ps[8];
    if (lane == 0) { ps[wid] = so; ps[4 + wid] = ss; }
    __syncthreads();
    if (threadIdx.x == 0) {
        atomicAdd(scal + 0, ps[0] + ps[1] + ps[2] + ps[3]);
        atomicAdd(scal + 1, ps[4] + ps[5] + ps[6] + ps[7]);
    }
}

__global__ void k_final(const float* __restrict__ scal, const float* __restrict__ blin,
                        float* __restrict__ out) {
    out[0] = (scal[0] + (float)NN * blin[0]) / scal[1];
}

extern "C" void kernel_launch(void* const* d_in, const int* in_sizes, int n_in,
                              void* d_out, int out_size, void* d_ws, size_t ws_size,
                              hipStream_t stream) {
    const float* x    = (const float*)d_in[0];
    const int*   ei   = (const int*)d_in[1];
    const float* surf = (const float*)d_in[2];
    const float* Wf1  = (const float*)d_in[3];
    const float* bf1  = (const float*)d_in[4];
    const float* Ws1  = (const float*)d_in[5];
    const float* bs1  = (const float*)d_in[6];
    const float* Wf2  = (const float*)d_in[7];
    const float* bf2  = (const float*)d_in[8];
    const float* Ws2  = (const float*)d_in[9];
    const float* bs2  = (const float*)d_in[10];
    const float* Wlin = (const float*)d_in[11];
    const float* blin = (const float*)d_in[12];

    unsigned char* ws = (unsigned char*)d_ws;
    int* deg    = (int*)(ws);                                // 401,408 (2*N2)
    int* csum   = (int*)(ws + 401408);                       // 512
    float* scal = (float*)(ws + 401920);                     // 64
    int* start  = (int*)(ws + 401984);                       // 401,408
    int* cursor = (int*)(ws + 803392);                       // 401,408
    int* esrc   = (int*)(ws + 1204800);                      // 3,200,000
    unsigned short* h1b  = (unsigned short*)(ws + 4404800);  // 6,406,144
    unsigned short* Pd   = (unsigned short*)(ws + 10810944); // 12,812,288
    unsigned char*  Ps   = (unsigned char*)(ws + 23623232);  // 6,406,144 (fp8)
    unsigned short* aggA = (unsigned short*)(ws + 30029376); // 6,406,144
    unsigned short* aggB = (unsigned short*)(ws + 36435520); // 6,406,144
    unsigned short* wt   = (unsigned short*)(ws + 42841664); // 65,536

    hipMemsetAsync(d_ws, 0, 401984, stream);  // deg + csum + scal

    k_deg_prep<<<3125, 256, 0, stream>>>(ei, deg, Wf1, Ws1, Wf2, Ws2, wt);
    k_scan1<<<98, 1024, 0, stream>>>(deg, start, csum);
    k_scan23<<<98, 1024, 0, stream>>>(start, csum, cursor);
    k_fill<<<3125, 256, 0, stream>>>(ei, cursor, esrc);

    k_proj<true><<<NTILE, 256, 0, stream>>>(x, wt, bf1, bs1, Pd, Ps);
    k_glean<0><<<2048, 256, 0, stream>>>((const unsigned int*)Pd, (const unsigned short*)Ps,
                                         esrc, start, aggA);
    k_glean<1><<<2048, 256, 0, stream>>>((const unsigned int*)Pd, (const unsigned short*)Ps,
                                         esrc, start, aggB);
    k_post1<<<3125, 256, 0, stream>>>(x, aggA, aggB, h1b);

    k_proj<false><<<NTILE, 256, 0, stream>>>(h1b, wt + 16384, bf2, bs2, Pd, Ps);
    k_glean<0><<<2048, 256, 0, stream>>>((const unsigned int*)Pd, (const unsigned short*)Ps,
                                         esrc, start, aggA);
    k_glean<1><<<2048, 256, 0, stream>>>((const unsigned int*)Pd, (const unsigned short*)Ps,
                                         esrc, start, aggB);
    k_post2<<<512, 256, 0, stream>>>(h1b, aggA, aggB, surf, Wlin, scal);
    k_final<<<1, 1, 0, stream>>>(scal, blin, (float*)d_out);
}

// Round 12
// 278.730 us; speedup vs baseline: 1.3104x; 1.0786x over previous
//
#include <hip/hip_runtime.h>

// CGConv x2 + masked readout. N=50000, E=800000, C=64.
// R12: VMEM-free flush. Wave stages edge indices + node-ends + its <=16 Pd
// rows + agg accumulator rows ALL in LDS; edge loop's only VMEM stream is the
// two-bank Ps loads (statically countable vmcnt). Flush = LDS-only. Agg rows
// dumped coalesced at wave end. Single CSR (src-split reverted: falsified).
// Residual/readout in separate streaming kernels (post1/post2).
//
// ws: deg(200704) csum(256) scal(64) start(200704) cursor(200704) esrc(3.2M)
//     h1b(6.4M) Pd(12.8M) Ps(6.4M fp8) agg(6.4M) wt(64K)

#define NN 50000
#define EE 800000
#define N2 50176          // 49*1024
#define NTILE 782
#define NWAVES 8192
#define EPW 98            // ceil(EE/NWAVES)

typedef short bf16x8 __attribute__((ext_vector_type(8)));
typedef float f32x4 __attribute__((ext_vector_type(4)));
typedef unsigned int uint4v __attribute__((ext_vector_type(4)));
typedef unsigned short u16x4 __attribute__((ext_vector_type(4)));
typedef int int4v __attribute__((ext_vector_type(4)));

#define LN2F 0.6931471805599453f
#define L2EF 1.4426950408889634f

#if __has_builtin(__builtin_amdgcn_exp2f)
#define EXP2(x) __builtin_amdgcn_exp2f(x)
#else
#define EXP2(x) __expf(LN2F * (x))
#endif
#if __has_builtin(__builtin_amdgcn_logf)
#define LOG2(x) __builtin_amdgcn_logf(x)
#else
#define LOG2(x) (L2EF * __logf(x))
#endif
#if __has_builtin(__builtin_amdgcn_rcpf)
#define RCPF(x) __builtin_amdgcn_rcpf(x)
#else
#define RCPF(x) (1.0f / (x))
#endif

__device__ __forceinline__ unsigned short f2b(float f) {
    unsigned int u = __builtin_bit_cast(unsigned int, f);
    return (unsigned short)((u + 0x7fffu + ((u >> 16) & 1u)) >> 16);
}
__device__ __forceinline__ float b2f(unsigned short b) {
    unsigned int u = ((unsigned int)b) << 16;
    return __builtin_bit_cast(float, u);
}
__device__ __forceinline__ float lo16f(unsigned int v) {
    return __builtin_bit_cast(float, v << 16);
}
__device__ __forceinline__ float hi16f(unsigned int v) {
    return __builtin_bit_cast(float, v & 0xFFFF0000u);
}

__device__ __forceinline__ unsigned char f2fp8(float f) {
#if __has_builtin(__builtin_amdgcn_cvt_pk_fp8_f32)
    return (unsigned char)(__builtin_amdgcn_cvt_pk_fp8_f32(f, f, 0, false) & 0xff);
#else
    float a = fabsf(f); if (a > 448.f) a = 448.f;
    int e2; float m = frexpf(a, &e2);
    int E = e2 + 6;
    unsigned char r;
    if (a < 0.001953125f) {
        r = (unsigned char)(a * 512.f + 0.5f);
    } else {
        int mant = (int)(m * 16.f + 0.5f) - 8;
        if (mant == 8) { mant = 0; ++E; }
        if (E > 15) { E = 15; mant = 7; }
        r = (unsigned char)((E << 3) | mant);
    }
    return r | (f < 0.f ? 0x80 : 0);
#endif
}
__device__ __forceinline__ float fp8lo(unsigned int v) {
#if __has_builtin(__builtin_amdgcn_cvt_f32_fp8)
    return __builtin_amdgcn_cvt_f32_fp8(v, 0);
#else
    unsigned b = v & 0xff;
    unsigned s = b >> 7, e = (b >> 3) & 15, mn = b & 7;
    float mag = e ? __builtin_ldexpf(1.f + mn * 0.125f, (int)e - 7)
                  : __builtin_ldexpf((float)mn, -9);
    return s ? -mag : mag;
#endif
}
__device__ __forceinline__ float fp8hi(unsigned int v) {
#if __has_builtin(__builtin_amdgcn_cvt_f32_fp8)
    return __builtin_amdgcn_cvt_f32_fp8(v, 1);
#else
    return fp8lo(v >> 8);
#endif
}

// per-edge message / ln2, pre-scaled: nF = -log2e*F, Sp = log2e*S
__device__ __forceinline__ float msg2(float nF, float Sp) {
    return RCPF(1.f + EXP2(nF)) * LOG2(1.f + EXP2(Sp));
}

// deg count + (blocks 0..127) weight prep.
__global__ __launch_bounds__(256) void k_deg_prep(const int* __restrict__ ei, int* __restrict__ deg,
                                                  const float* __restrict__ Wf1, const float* __restrict__ Ws1,
                                                  const float* __restrict__ Wf2, const float* __restrict__ Ws2,
                                                  unsigned short* __restrict__ wt) {
    int e = blockIdx.x * 256 + threadIdx.x;
    if (blockIdx.x < 128) {
        int i = e;
        int layer = i >> 14;
        int j = i & 16383;
        int n = j >> 6, k = j & 63;
        const float* Wf = layer ? Wf2 : Wf1;
        const float* Ws = layer ? Ws2 : Ws1;
        float v;
        if (n < 64)       v = Wf[k * 64 + n];
        else if (n < 128) v = Ws[k * 64 + (n - 64)];
        else if (n < 192) v = Wf[(64 + k) * 64 + (n - 128)];
        else              v = Ws[(64 + k) * 64 + (n - 192)];
        int byte = ((n * 128 + k * 2) ^ ((n & 7) << 4)) + layer * 32768;
        *(unsigned short*)((char*)wt + byte) = f2b(v);
    }
    atomicAdd(&deg[ei[EE + e]], 1);
}

__global__ __launch_bounds__(1024) void k_scan1(const int* __restrict__ deg, int* __restrict__ start,
                                                int* __restrict__ csum) {
    __shared__ int s[1024];
    int t = threadIdx.x;
    int i = blockIdx.x * 1024 + t;
    int v = deg[i];
    s[t] = v; __syncthreads();
    for (int off = 1; off < 1024; off <<= 1) {
        int y = (t >= off) ? s[t - off] : 0; __syncthreads();
        s[t] += y; __syncthreads();
    }
    start[i] = s[t] - v;
    if (t == 1023) csum[blockIdx.x] = s[t];
}

__global__ __launch_bounds__(1024) void k_scan23(int* __restrict__ start, const int* __restrict__ csum,
                                                 int* __restrict__ cursor) {
    __shared__ int red[1024];
    int t = threadIdx.x;
    red[t] = (t < (int)blockIdx.x) ? csum[t] : 0;
    __syncthreads();
    for (int off = 512; off; off >>= 1) {
        if (t < off) red[t] += red[t + off];
        __syncthreads();
    }
    int base = red[0];
    int i = blockIdx.x * 1024 + t;
    int nv = start[i] + base;
    start[i] = nv;
    cursor[i] = nv;
}

__global__ __launch_bounds__(256) void k_fill(const int* __restrict__ ei, int* __restrict__ cursor,
                                              int* __restrict__ esrc) {
    int e = blockIdx.x * 256 + threadIdx.x;
    int dst = ei[EE + e];
    int p = atomicAdd(&cursor[dst], 1);
    esrc[p] = ei[e];
}

// P = H @ Wcat, 64 nodes x 256 cols per block, 4 waves.
// Pd (per node, 64 dwords): [ -log2e*F_c (lo16 bf16) | log2e*S_c (hi16 bf16) ].
// Ps (per node, 64 ushorts): [ fp8(-log2e*(F_c+bf)) | fp8(log2e*(S_c+bs)) ].
template <bool F32IN>
__global__ __launch_bounds__(256) void k_proj(const void* __restrict__ hin,
                                              const unsigned short* __restrict__ wt,
                                              const float* __restrict__ bfv, const float* __restrict__ bsv,
                                              unsigned short* __restrict__ Pd, unsigned char* __restrict__ Ps) {
    __shared__ unsigned short w_s[256 * 64];
    __shared__ unsigned short a_s[64 * 64];
    const int t = threadIdx.x;
    {
        const uint4v* src = (const uint4v*)wt;
        uint4v* dp = (uint4v*)w_s;
        #pragma unroll
        for (int i = 0; i < 8; ++i) dp[t + 256 * i] = src[t + 256 * i];
    }
    const int lane = t & 63, wid = t >> 6;
    const int cbase = lane & 15, q = lane >> 4;
    const int tile = blockIdx.x;

    #pragma unroll
    for (int i = 0; i < 2; ++i) {
        int ch = t + 256 * i;
        int r = ch >> 3, c8 = ch & 7;
        int node = tile * 64 + r;
        u16x4 lo = {0, 0, 0, 0}, hi = {0, 0, 0, 0};
        if (node < NN) {
            if (F32IN) {
                const float* xp = (const float*)hin + node * 64 + c8 * 8;
                f32x4 v0 = *(const f32x4*)xp;
                f32x4 v1 = *(const f32x4*)(xp + 4);
                lo[0] = f2b(v0[0]); lo[1] = f2b(v0[1]); lo[2] = f2b(v0[2]); lo[3] = f2b(v0[3]);
                hi[0] = f2b(v1[0]); hi[1] = f2b(v1[1]); hi[2] = f2b(v1[2]); hi[3] = f2b(v1[3]);
            } else {
                const unsigned short* hp = (const unsigned short*)hin + node * 64 + c8 * 8;
                lo = *(const u16x4*)hp;
                hi = *(const u16x4*)(hp + 4);
            }
        }
        int byte = (r * 128 + c8 * 16) ^ ((r & 7) << 4);
        *(u16x4*)((char*)a_s + byte) = lo;
        *(u16x4*)((char*)a_s + byte + 8) = hi;
    }
    __syncthreads();

    f32x4 acc[4][4];
    #pragma unroll
    for (int m = 0; m < 4; ++m)
        #pragma unroll
        for (int n = 0; n < 4; ++n) acc[m][n] = (f32x4){0.f, 0.f, 0.f, 0.f};

    #pragma unroll
    for (int ks = 0; ks < 2; ++ks) {
        bf16x8 a[4];
        #pragma unroll
        for (int m = 0; m < 4; ++m) {
            int mr = m * 16 + cbase;
            a[m] = *(const bf16x8*)((const char*)a_s + mr * 128 + ((ks * 64 + q * 16) ^ ((mr & 7) << 4)));
        }
        #pragma unroll
        for (int n = 0; n < 4; ++n) {
            int bn = wid * 64 + n * 16 + cbase;
            bf16x8 b = *(const bf16x8*)((const char*)w_s + bn * 128 + ((ks * 64 + q * 16) ^ ((bn & 7) << 4)));
            #pragma unroll
            for (int m = 0; m < 4; ++m)
                acc[m][n] = __builtin_amdgcn_mfma_f32_16x16x32_bf16(a[m], b, acc[m][n], 0, 0, 0);
        }
    }

    #pragma unroll
    for (int n = 0; n < 4; ++n) {
        int col = wid * 64 + n * 16 + cbase;
        if (col < 128) {
            int oidx = (col < 64) ? 2 * col : 2 * (col - 64) + 1;
            float scale = (col < 64) ? -L2EF : L2EF;
            #pragma unroll
            for (int m = 0; m < 4; ++m) {
                int node = tile * 64 + m * 16 + q * 4;
                #pragma unroll
                for (int r = 0; r < 4; ++r)
                    Pd[(node + r) * 128 + oidx] = f2b(acc[m][n][r] * scale);
            }
        } else {
            float bias, scale; int boff;
            if (col < 192) { scale = -L2EF; bias = bfv[col - 128]; boff = 2 * (col - 128); }
            else           { scale =  L2EF; bias = bsv[col - 192]; boff = 2 * (col - 192) + 1; }
            #pragma unroll
            for (int m = 0; m < 4; ++m) {
                int node = tile * 64 + m * 16 + q * 4;
                #pragma unroll
                for (int r = 0; r < 4; ++r)
                    Ps[(node + r) * 128 + boff] = f2fp8((acc[m][n][r] + bias) * scale);
            }
        }
    }
}

// Gather: all per-node state (edge idx, node ends, Pd rows, agg rows) in LDS.
// Edge loop's ONLY VMEM stream = Ps loads (two 8-wide banks, countable vmcnt).
// Flush is LDS-only. Agg rows dumped coalesced at wave end.
__global__ __launch_bounds__(256) void k_glean(const unsigned int* __restrict__ Pd,
                                               const unsigned short* __restrict__ Ps,
                                               const int* __restrict__ esrc, const int* __restrict__ start,
                                               unsigned short* __restrict__ agg) {
    __shared__ int idx_s[4][208];
    __shared__ int end_s[4][32];
    __shared__ unsigned int pd_s[4][1024];     // 16 nodes x 64 lanes
    __shared__ unsigned short ag_s[4][1024];   // 16 nodes x 64 lanes
    const int lane = threadIdx.x & 63;
    const int wid = threadIdx.x >> 6;
    const int w = blockIdx.x * 4 + wid;

    int t0 = w * EPW, t1 = t0 + EPW;
    int lo = 0, hi = NN;
    while (lo < hi) { int mid = (lo + hi) >> 1; if (start[mid] < t0) lo = mid + 1; else hi = mid; }
    const int n0 = lo;
    hi = NN;
    while (lo < hi) { int mid = (lo + hi) >> 1; if (start[mid] < t1) lo = mid + 1; else hi = mid; }
    const int n1 = lo;
    const int nn = n1 - n0;
    const int nn16 = (nn < 16) ? nn : 16;

    const int e0 = __builtin_amdgcn_readfirstlane(start[n0]);
    const int cnt = __builtin_amdgcn_readfirstlane(start[n1]) - e0;
    int* idxp = idx_s[wid];
    for (int k = lane; k < cnt + 16; k += 64)
        idxp[k] = (k < cnt) ? esrc[e0 + k] : 0;
    int* endp = end_s[wid];
    if (lane < 32)
        endp[lane] = (lane < nn && lane < 31) ? (start[n0 + 1 + lane] - e0) : 0x7fffffff;
    unsigned int* pdp = pd_s[wid];
    for (int i = 0; i < nn16; ++i)
        pdp[i * 64 + lane] = Pd[(n0 + i) * 64 + lane];
    unsigned short* agp = ag_s[wid];

    int n = n0;
    int nend = 0x7fffffff;
    float acc = 0.f, nfd = 0.f, sd = 0.f;
    if (nn > 0) {
        unsigned int pv = pdp[lane];
        nfd = lo16f(pv); sd = hi16f(pv);
        nend = endp[0];
    }

#define FLUSH() do {                                                          \
    int io_ = n - n0;                                                         \
    if (io_ < 16) agp[io_ * 64 + lane] = f2b(acc);                            \
    else agg[n * 64 + lane] = f2b(acc);                                       \
    ++n; acc = 0.f;                                                           \
    int ii_ = n - n0;                                                         \
    unsigned int pv_;                                                         \
    if (ii_ < 16) pv_ = pdp[ii_ * 64 + lane];                                 \
    else pv_ = Pd[((n < NN) ? n : NN - 1) * 64 + lane];                       \
    nfd = lo16f(pv_); sd = hi16f(pv_);                                        \
    nend = (ii_ < 31) ? endp[ii_]                                             \
                      : (__builtin_amdgcn_readfirstlane(start[n + 1]) - e0);  \
} while (0)

#define LOADB(vv, kb_) do {                                                   \
    int4v j0_ = *(const int4v*)(idxp + (kb_));                                \
    int4v j1_ = *(const int4v*)(idxp + (kb_) + 4);                            \
    vv[0] = Ps[j0_[0] * 64 + lane]; vv[1] = Ps[j0_[1] * 64 + lane];           \
    vv[2] = Ps[j0_[2] * 64 + lane]; vv[3] = Ps[j0_[3] * 64 + lane];           \
    vv[4] = Ps[j1_[0] * 64 + lane]; vv[5] = Ps[j1_[1] * 64 + lane];           \
    vv[6] = Ps[j1_[2] * 64 + lane]; vv[7] = Ps[j1_[3] * 64 + lane];           \
} while (0)

#define COMP(vv, kb_) do {                                                    \
    _Pragma("unroll")                                                         \
    for (int i_ = 0; i_ < 8; ++i_) {                                          \
        int k_ = (kb_) + i_;                                                  \
        while (k_ == nend && n < n1) FLUSH();                                 \
        float m_ = msg2(nfd + fp8lo(vv[i_]), sd + fp8hi(vv[i_]));             \
        if (k_ < cnt) acc += m_;                                              \
    }                                                                         \
} while (0)

    if (cnt > 0) {
        unsigned int vA[8], vB[8];
        LOADB(vA, 0);
        int kb = 0;
        while (true) {
            LOADB(vB, kb + 8);
            COMP(vA, kb);
            kb += 8; if (kb >= cnt) break;
            LOADB(vA, kb + 8);
            COMP(vB, kb);
            kb += 8; if (kb >= cnt) break;
        }
    }
    while (n < n1) FLUSH();
#undef FLUSH
#undef LOADB
#undef COMP

    // dump staged agg rows (coalesced 128B stores)
    for (int i = 0; i < nn16; ++i)
        agg[(n0 + i) * 64 + lane] = agp[i * 64 + lane];
}

// h1 = x + ln2*agg, streamed, vectorized; h1b in bf16.
__global__ __launch_bounds__(256) void k_post1(const float* __restrict__ x,
                                               const unsigned short* __restrict__ agg,
                                               unsigned short* __restrict__ h1b) {
    int i = (blockIdx.x * 256 + threadIdx.x) * 4;
    f32x4 xv = *(const f32x4*)(x + i);
    u16x4 a = *(const u16x4*)(agg + i);
    u16x4 o;
    #pragma unroll
    for (int j = 0; j < 4; ++j)
        o[j] = f2b(xv[j] + LN2F * b2f(a[j]));
    *(u16x4*)(h1b + i) = o;
}

// readout: h2 = h1 + ln2*agg2; so += surf * (h2 . Wlin); ss += surf.
__global__ __launch_bounds__(256) void k_post2(const unsigned short* __restrict__ h1b,
                                               const unsigned short* __restrict__ agg,
                                               const float* __restrict__ surf, const float* __restrict__ Wlin,
                                               float* __restrict__ scal) {
    const int lane = threadIdx.x & 63, wid = threadIdx.x >> 6;
    float wl = Wlin[lane];
    float so = 0.f, ss = 0.f;
    for (int n = blockIdx.x * 4 + wid; n < NN; n += gridDim.x * 4) {
        int i = n * 64 + lane;
        float h2 = b2f(h1b[i]) + LN2F * b2f(agg[i]);
        float v = h2 * wl;
        #pragma unroll
        for (int off = 32; off; off >>= 1) v += __shfl_xor(v, off);
        if (lane == 0) { so += v * surf[n]; ss += surf[n]; }
    }
    __shared__ float ps[8];
    if (lane == 0) { ps[wid] = so; ps[4 + wid] = ss; }
    __syncthreads();
    if (threadIdx.x == 0) {
        atomicAdd(scal + 0, ps[0] + ps[1] + ps[2] + ps[3]);
        atomicAdd(scal + 1, ps[4] + ps[5] + ps[6] + ps[7]);
    }
}

__global__ void k_final(const float* __restrict__ scal, const float* __restrict__ blin,
                        float* __restrict__ out) {
    out[0] = (scal[0] + (float)NN * blin[0]) / scal[1];
}

extern "C" void kernel_launch(void* const* d_in, const int* in_sizes, int n_in,
                              void* d_out, int out_size, void* d_ws, size_t ws_size,
                              hipStream_t stream) {
    const float* x    = (const float*)d_in[0];
    const int*   ei   = (const int*)d_in[1];
    const float* surf = (const float*)d_in[2];
    const float* Wf1  = (const float*)d_in[3];
    const float* bf1  = (const float*)d_in[4];
    const float* Ws1  = (const float*)d_in[5];
    const float* bs1  = (const float*)d_in[6];
    const float* Wf2  = (const float*)d_in[7];
    const float* bf2  = (const float*)d_in[8];
    const float* Ws2  = (const float*)d_in[9];
    const float* bs2  = (const float*)d_in[10];
    const float* Wlin = (const float*)d_in[11];
    const float* blin = (const float*)d_in[12];

    unsigned char* ws = (unsigned char*)d_ws;
    int* deg    = (int*)(ws);                                // 200,704
    int* csum   = (int*)(ws + 200704);                       // 256
    float* scal = (float*)(ws + 200960);                     // 64
    int* start  = (int*)(ws + 201024);                       // 200,704
    int* cursor = (int*)(ws + 401728);                       // 200,704
    int* esrc   = (int*)(ws + 602432);                       // 3,200,000
    unsigned short* h1b = (unsigned short*)(ws + 3802432);   // 6,406,144
    unsigned short* Pd  = (unsigned short*)(ws + 10208576);  // 12,812,288
    unsigned char*  Ps  = (unsigned char*)(ws + 23020864);   // 6,406,144 (fp8)
    unsigned short* agg = (unsigned short*)(ws + 29427008);  // 6,406,144
    unsigned short* wt  = (unsigned short*)(ws + 35833152);  // 65,536

    hipMemsetAsync(d_ws, 0, 201024, stream);  // deg + csum + scal

    k_deg_prep<<<3125, 256, 0, stream>>>(ei, deg, Wf1, Ws1, Wf2, Ws2, wt);
    k_scan1<<<49, 1024, 0, stream>>>(deg, start, csum);
    k_scan23<<<49, 1024, 0, stream>>>(start, csum, cursor);
    k_fill<<<3125, 256, 0, stream>>>(ei, cursor, esrc);

    k_proj<true><<<NTILE, 256, 0, stream>>>(x, wt, bf1, bs1, Pd, Ps);
    k_glean<<<2048, 256, 0, stream>>>((const unsigned int*)Pd, (const unsigned short*)Ps,
                                      esrc, start, agg);
    k_post1<<<3125, 256, 0, stream>>>(x, agg, h1b);

    k_proj<false><<<NTILE, 256, 0, stream>>>(h1b, wt + 16384, bf2, bs2, Pd, Ps);
    k_glean<<<2048, 256, 0, stream>>>((const unsigned int*)Pd, (const unsigned short*)Ps,
                                      esrc, start, agg);
    k_post2<<<512, 256, 0, stream>>>(h1b, agg, surf, Wlin, scal);
    k_final<<<1, 1, 0, stream>>>(scal, blin, (float*)d_out);
}

// Round 13
// 256.194 us; speedup vs baseline: 1.4257x; 1.0880x over previous
//
#include <hip/hip_runtime.h>

// CGConv x2 + masked readout. N=50000, E=800000, C=64.
// R13: (a) glean drops the LDS agg staging -- direct agg stores in FLUSH
// (stores are fire-and-forget; only LOAD consumption drained the pipe, R10
// MODE1). LDS 28KB -> 20KB -> 8 blocks/CU. (b) post1 fused into layer-2 proj
// (reads x+agg, writes h1b, stages bf16(h)) -- one less 19MB pass + launch.
//
// ws: deg(200704) csum(256) scal(64) start(200704) cursor(200704) esrc(3.2M)
//     h1b(6.4M) Pd(12.8M) Ps(6.4M fp8) agg(6.4M) wt(64K)

#define NN 50000
#define EE 800000
#define N2 50176
#define NTILE 782
#define NWAVES 8192
#define EPW 98

typedef short bf16x8 __attribute__((ext_vector_type(8)));
typedef float f32x4 __attribute__((ext_vector_type(4)));
typedef unsigned int uint4v __attribute__((ext_vector_type(4)));
typedef unsigned short u16x4 __attribute__((ext_vector_type(4)));
typedef int int4v __attribute__((ext_vector_type(4)));

#define LN2F 0.6931471805599453f
#define L2EF 1.4426950408889634f

#if __has_builtin(__builtin_amdgcn_exp2f)
#define EXP2(x) __builtin_amdgcn_exp2f(x)
#else
#define EXP2(x) __expf(LN2F * (x))
#endif
#if __has_builtin(__builtin_amdgcn_logf)
#define LOG2(x) __builtin_amdgcn_logf(x)
#else
#define LOG2(x) (L2EF * __logf(x))
#endif
#if __has_builtin(__builtin_amdgcn_rcpf)
#define RCPF(x) __builtin_amdgcn_rcpf(x)
#else
#define RCPF(x) (1.0f / (x))
#endif

__device__ __forceinline__ unsigned short f2b(float f) {
    unsigned int u = __builtin_bit_cast(unsigned int, f);
    return (unsigned short)((u + 0x7fffu + ((u >> 16) & 1u)) >> 16);
}
__device__ __forceinline__ float b2f(unsigned short b) {
    unsigned int u = ((unsigned int)b) << 16;
    return __builtin_bit_cast(float, u);
}
__device__ __forceinline__ float lo16f(unsigned int v) {
    return __builtin_bit_cast(float, v << 16);
}
__device__ __forceinline__ float hi16f(unsigned int v) {
    return __builtin_bit_cast(float, v & 0xFFFF0000u);
}

__device__ __forceinline__ unsigned char f2fp8(float f) {
#if __has_builtin(__builtin_amdgcn_cvt_pk_fp8_f32)
    return (unsigned char)(__builtin_amdgcn_cvt_pk_fp8_f32(f, f, 0, false) & 0xff);
#else
    float a = fabsf(f); if (a > 448.f) a = 448.f;
    int e2; float m = frexpf(a, &e2);
    int E = e2 + 6;
    unsigned char r;
    if (a < 0.001953125f) {
        r = (unsigned char)(a * 512.f + 0.5f);
    } else {
        int mant = (int)(m * 16.f + 0.5f) - 8;
        if (mant == 8) { mant = 0; ++E; }
        if (E > 15) { E = 15; mant = 7; }
        r = (unsigned char)((E << 3) | mant);
    }
    return r | (f < 0.f ? 0x80 : 0);
#endif
}
__device__ __forceinline__ float fp8lo(unsigned int v) {
#if __has_builtin(__builtin_amdgcn_cvt_f32_fp8)
    return __builtin_amdgcn_cvt_f32_fp8(v, 0);
#else
    unsigned b = v & 0xff;
    unsigned s = b >> 7, e = (b >> 3) & 15, mn = b & 7;
    float mag = e ? __builtin_ldexpf(1.f + mn * 0.125f, (int)e - 7)
                  : __builtin_ldexpf((float)mn, -9);
    return s ? -mag : mag;
#endif
}
__device__ __forceinline__ float fp8hi(unsigned int v) {
#if __has_builtin(__builtin_amdgcn_cvt_f32_fp8)
    return __builtin_amdgcn_cvt_f32_fp8(v, 1);
#else
    return fp8lo(v >> 8);
#endif
}

// per-edge message / ln2, pre-scaled: nF = -log2e*F, Sp = log2e*S
__device__ __forceinline__ float msg2(float nF, float Sp) {
    return RCPF(1.f + EXP2(nF)) * LOG2(1.f + EXP2(Sp));
}

// deg count + (blocks 0..127) weight prep.
__global__ __launch_bounds__(256) void k_deg_prep(const int* __restrict__ ei, int* __restrict__ deg,
                                                  const float* __restrict__ Wf1, const float* __restrict__ Ws1,
                                                  const float* __restrict__ Wf2, const float* __restrict__ Ws2,
                                                  unsigned short* __restrict__ wt) {
    int e = blockIdx.x * 256 + threadIdx.x;
    if (blockIdx.x < 128) {
        int i = e;
        int layer = i >> 14;
        int j = i & 16383;
        int n = j >> 6, k = j & 63;
        const float* Wf = layer ? Wf2 : Wf1;
        const float* Ws = layer ? Ws2 : Ws1;
        float v;
        if (n < 64)       v = Wf[k * 64 + n];
        else if (n < 128) v = Ws[k * 64 + (n - 64)];
        else if (n < 192) v = Wf[(64 + k) * 64 + (n - 128)];
        else              v = Ws[(64 + k) * 64 + (n - 192)];
        int byte = ((n * 128 + k * 2) ^ ((n & 7) << 4)) + layer * 32768;
        *(unsigned short*)((char*)wt + byte) = f2b(v);
    }
    atomicAdd(&deg[ei[EE + e]], 1);
}

__global__ __launch_bounds__(1024) void k_scan1(const int* __restrict__ deg, int* __restrict__ start,
                                                int* __restrict__ csum) {
    __shared__ int s[1024];
    int t = threadIdx.x;
    int i = blockIdx.x * 1024 + t;
    int v = deg[i];
    s[t] = v; __syncthreads();
    for (int off = 1; off < 1024; off <<= 1) {
        int y = (t >= off) ? s[t - off] : 0; __syncthreads();
        s[t] += y; __syncthreads();
    }
    start[i] = s[t] - v;
    if (t == 1023) csum[blockIdx.x] = s[t];
}

__global__ __launch_bounds__(1024) void k_scan23(int* __restrict__ start, const int* __restrict__ csum,
                                                 int* __restrict__ cursor) {
    __shared__ int red[1024];
    int t = threadIdx.x;
    red[t] = (t < (int)blockIdx.x) ? csum[t] : 0;
    __syncthreads();
    for (int off = 512; off; off >>= 1) {
        if (t < off) red[t] += red[t + off];
        __syncthreads();
    }
    int base = red[0];
    int i = blockIdx.x * 1024 + t;
    int nv = start[i] + base;
    start[i] = nv;
    cursor[i] = nv;
}

__global__ __launch_bounds__(256) void k_fill(const int* __restrict__ ei, int* __restrict__ cursor,
                                              int* __restrict__ esrc) {
    int e = blockIdx.x * 256 + threadIdx.x;
    int dst = ei[EE + e];
    int p = atomicAdd(&cursor[dst], 1);
    esrc[p] = ei[e];
}

// P = H @ Wcat, 64 nodes x 256 cols per block, 4 waves.
// MODE 0: layer1, input = x (f32).
// MODE 1: layer2 fused residual: h = x + ln2*agg; writes h1b; stages bf16(h).
// Pd (per node, 64 dwords): [ -log2e*F_c (lo16 bf16) | log2e*S_c (hi16 bf16) ].
// Ps (per node, 64 ushorts): [ fp8(-log2e*(F_c+bf)) | fp8(log2e*(S_c+bs)) ].
template <int MODE>
__global__ __launch_bounds__(256) void k_proj(const float* __restrict__ x,
                                              const unsigned short* __restrict__ agg,
                                              unsigned short* __restrict__ h1b,
                                              const unsigned short* __restrict__ wt,
                                              const float* __restrict__ bfv, const float* __restrict__ bsv,
                                              unsigned short* __restrict__ Pd, unsigned char* __restrict__ Ps) {
    __shared__ unsigned short w_s[256 * 64];
    __shared__ unsigned short a_s[64 * 64];
    const int t = threadIdx.x;
    {
        const uint4v* src = (const uint4v*)wt;
        uint4v* dp = (uint4v*)w_s;
        #pragma unroll
        for (int i = 0; i < 8; ++i) dp[t + 256 * i] = src[t + 256 * i];
    }
    const int lane = t & 63, wid = t >> 6;
    const int cbase = lane & 15, q = lane >> 4;
    const int tile = blockIdx.x;

    #pragma unroll
    for (int i = 0; i < 2; ++i) {
        int ch = t + 256 * i;
        int r = ch >> 3, c8 = ch & 7;
        int node = tile * 64 + r;
        u16x4 lo = {0, 0, 0, 0}, hi = {0, 0, 0, 0};
        if (node < NN) {
            const float* xp = x + node * 64 + c8 * 8;
            f32x4 v0 = *(const f32x4*)xp;
            f32x4 v1 = *(const f32x4*)(xp + 4);
            if (MODE == 1) {
                const unsigned short* ap = agg + node * 64 + c8 * 8;
                u16x4 a0 = *(const u16x4*)ap;
                u16x4 a1 = *(const u16x4*)(ap + 4);
                #pragma unroll
                for (int j = 0; j < 4; ++j) {
                    v0[j] += LN2F * b2f(a0[j]);
                    v1[j] += LN2F * b2f(a1[j]);
                }
            }
            lo[0] = f2b(v0[0]); lo[1] = f2b(v0[1]); lo[2] = f2b(v0[2]); lo[3] = f2b(v0[3]);
            hi[0] = f2b(v1[0]); hi[1] = f2b(v1[1]); hi[2] = f2b(v1[2]); hi[3] = f2b(v1[3]);
            if (MODE == 1) {
                unsigned short* hp = h1b + node * 64 + c8 * 8;
                *(u16x4*)hp = lo;
                *(u16x4*)(hp + 4) = hi;
            }
        }
        int byte = (r * 128 + c8 * 16) ^ ((r & 7) << 4);
        *(u16x4*)((char*)a_s + byte) = lo;
        *(u16x4*)((char*)a_s + byte + 8) = hi;
    }
    __syncthreads();

    f32x4 acc[4][4];
    #pragma unroll
    for (int m = 0; m < 4; ++m)
        #pragma unroll
        for (int n = 0; n < 4; ++n) acc[m][n] = (f32x4){0.f, 0.f, 0.f, 0.f};

    #pragma unroll
    for (int ks = 0; ks < 2; ++ks) {
        bf16x8 a[4];
        #pragma unroll
        for (int m = 0; m < 4; ++m) {
            int mr = m * 16 + cbase;
            a[m] = *(const bf16x8*)((const char*)a_s + mr * 128 + ((ks * 64 + q * 16) ^ ((mr & 7) << 4)));
        }
        #pragma unroll
        for (int n = 0; n < 4; ++n) {
            int bn = wid * 64 + n * 16 + cbase;
            bf16x8 b = *(const bf16x8*)((const char*)w_s + bn * 128 + ((ks * 64 + q * 16) ^ ((bn & 7) << 4)));
            #pragma unroll
            for (int m = 0; m < 4; ++m)
                acc[m][n] = __builtin_amdgcn_mfma_f32_16x16x32_bf16(a[m], b, acc[m][n], 0, 0, 0);
        }
    }

    #pragma unroll
    for (int n = 0; n < 4; ++n) {
        int col = wid * 64 + n * 16 + cbase;
        if (col < 128) {
            int oidx = (col < 64) ? 2 * col : 2 * (col - 64) + 1;
            float scale = (col < 64) ? -L2EF : L2EF;
            #pragma unroll
            for (int m = 0; m < 4; ++m) {
                int node = tile * 64 + m * 16 + q * 4;
                #pragma unroll
                for (int r = 0; r < 4; ++r)
                    Pd[(node + r) * 128 + oidx] = f2b(acc[m][n][r] * scale);
            }
        } else {
            float bias, scale; int boff;
            if (col < 192) { scale = -L2EF; bias = bfv[col - 128]; boff = 2 * (col - 128); }
            else           { scale =  L2EF; bias = bsv[col - 192]; boff = 2 * (col - 192) + 1; }
            #pragma unroll
            for (int m = 0; m < 4; ++m) {
                int node = tile * 64 + m * 16 + q * 4;
                #pragma unroll
                for (int r = 0; r < 4; ++r)
                    Ps[(node + r) * 128 + boff] = f2fp8((acc[m][n][r] + bias) * scale);
            }
        }
    }
}

// Gather: edge idx + node ends + Pd rows staged in LDS; agg stored DIRECTLY in
// flush (stores don't stall). Only VMEM stream in loop = Ps loads. LDS ~20KB.
__global__ __launch_bounds__(256) void k_glean(const unsigned int* __restrict__ Pd,
                                               const unsigned short* __restrict__ Ps,
                                               const int* __restrict__ esrc, const int* __restrict__ start,
                                               unsigned short* __restrict__ agg) {
    __shared__ int idx_s[4][208];
    __shared__ int end_s[4][32];
    __shared__ unsigned int pd_s[4][1024];     // 16 nodes x 64 lanes
    const int lane = threadIdx.x & 63;
    const int wid = threadIdx.x >> 6;
    const int w = blockIdx.x * 4 + wid;

    int t0 = w * EPW, t1 = t0 + EPW;
    int lo = 0, hi = NN;
    while (lo < hi) { int mid = (lo + hi) >> 1; if (start[mid] < t0) lo = mid + 1; else hi = mid; }
    const int n0 = lo;
    hi = NN;
    while (lo < hi) { int mid = (lo + hi) >> 1; if (start[mid] < t1) lo = mid + 1; else hi = mid; }
    const int n1 = lo;
    const int nn = n1 - n0;
    const int nn16 = (nn < 16) ? nn : 16;

    const int e0 = __builtin_amdgcn_readfirstlane(start[n0]);
    const int cnt = __builtin_amdgcn_readfirstlane(start[n1]) - e0;
    int* idxp = idx_s[wid];
    for (int k = lane; k < cnt + 16; k += 64)
        idxp[k] = (k < cnt) ? esrc[e0 + k] : 0;
    int* endp = end_s[wid];
    if (lane < 32)
        endp[lane] = (lane < nn && lane < 31) ? (start[n0 + 1 + lane] - e0) : 0x7fffffff;
    unsigned int* pdp = pd_s[wid];
    for (int i = 0; i < nn16; ++i)
        pdp[i * 64 + lane] = Pd[(n0 + i) * 64 + lane];

    int n = n0;
    int nend = 0x7fffffff;
    float acc = 0.f, nfd = 0.f, sd = 0.f;
    if (nn > 0) {
        unsigned int pv = pdp[lane];
        nfd = lo16f(pv); sd = hi16f(pv);
        nend = endp[0];
    }

#define FLUSH() do {                                                          \
    agg[n * 64 + lane] = f2b(acc);                                            \
    ++n; acc = 0.f;                                                           \
    int ii_ = n - n0;                                                         \
    unsigned int pv_;                                                         \
    if (ii_ < 16) pv_ = pdp[ii_ * 64 + lane];                                 \
    else pv_ = Pd[((n < NN) ? n : NN - 1) * 64 + lane];                       \
    nfd = lo16f(pv_); sd = hi16f(pv_);                                        \
    nend = (ii_ < 31) ? endp[ii_]                                             \
                      : (__builtin_amdgcn_readfirstlane(start[n + 1]) - e0);  \
} while (0)

#define LOADB(vv, kb_) do {                                                   \
    int4v j0_ = *(const int4v*)(idxp + (kb_));                                \
    int4v j1_ = *(const int4v*)(idxp + (kb_) + 4);                            \
    vv[0] = Ps[j0_[0] * 64 + lane]; vv[1] = Ps[j0_[1] * 64 + lane];           \
    vv[2] = Ps[j0_[2] * 64 + lane]; vv[3] = Ps[j0_[3] * 64 + lane];           \
    vv[4] = Ps[j1_[0] * 64 + lane]; vv[5] = Ps[j1_[1] * 64 + lane];           \
    vv[6] = Ps[j1_[2] * 64 + lane]; vv[7] = Ps[j1_[3] * 64 + lane];           \
} while (0)

#define COMP(vv, kb_) do {                                                    \
    _Pragma("unroll")                                                         \
    for (int i_ = 0; i_ < 8; ++i_) {                                          \
        int k_ = (kb_) + i_;                                                  \
        while (k_ == nend && n < n1) FLUSH();                                 \
        float m_ = msg2(nfd + fp8lo(vv[i_]), sd + fp8hi(vv[i_]));             \
        if (k_ < cnt) acc += m_;                                              \
    }                                                                         \
} while (0)

    if (cnt > 0) {
        unsigned int vA[8], vB[8];
        LOADB(vA, 0);
        int kb = 0;
        while (true) {
            LOADB(vB, kb + 8);
            COMP(vA, kb);
            kb += 8; if (kb >= cnt) break;
            LOADB(vA, kb + 8);
            COMP(vB, kb);
            kb += 8; if (kb >= cnt) break;
        }
    }
    while (n < n1) FLUSH();
#undef FLUSH
#undef LOADB
#undef COMP
}

// readout: h2 = h1 + ln2*agg2; so += surf * (h2 . Wlin); ss += surf.
__global__ __launch_bounds__(256) void k_post2(const unsigned short* __restrict__ h1b,
                                               const unsigned short* __restrict__ agg,
                                               const float* __restrict__ surf, const float* __restrict__ Wlin,
                                               float* __restrict__ scal) {
    const int lane = threadIdx.x & 63, wid = threadIdx.x >> 6;
    float wl = Wlin[lane];
    float so = 0.f, ss = 0.f;
    for (int n = blockIdx.x * 4 + wid; n < NN; n += gridDim.x * 4) {
        int i = n * 64 + lane;
        float h2 = b2f(h1b[i]) + LN2F * b2f(agg[i]);
        float v = h2 * wl;
        #pragma unroll
        for (int off = 32; off; off >>= 1) v += __shfl_xor(v, off);
        if (lane == 0) { so += v * surf[n]; ss += surf[n]; }
    }
    __shared__ float ps[8];
    if (lane == 0) { ps[wid] = so; ps[4 + wid] = ss; }
    __syncthreads();
    if (threadIdx.x == 0) {
        atomicAdd(scal + 0, ps[0] + ps[1] + ps[2] + ps[3]);
        atomicAdd(scal + 1, ps[4] + ps[5] + ps[6] + ps[7]);
    }
}

__global__ void k_final(const float* __restrict__ scal, const float* __restrict__ blin,
                        float* __restrict__ out) {
    out[0] = (scal[0] + (float)NN * blin[0]) / scal[1];
}

extern "C" void kernel_launch(void* const* d_in, const int* in_sizes, int n_in,
                              void* d_out, int out_size, void* d_ws, size_t ws_size,
                              hipStream_t stream) {
    const float* x    = (const float*)d_in[0];
    const int*   ei   = (const int*)d_in[1];
    const float* surf = (const float*)d_in[2];
    const float* Wf1  = (const float*)d_in[3];
    const float* bf1  = (const float*)d_in[4];
    const float* Ws1  = (const float*)d_in[5];
    const float* bs1  = (const float*)d_in[6];
    const float* Wf2  = (const float*)d_in[7];
    const float* bf2  = (const float*)d_in[8];
    const float* Ws2  = (const float*)d_in[9];
    const float* bs2  = (const float*)d_in[10];
    const float* Wlin = (const float*)d_in[11];
    const float* blin = (const float*)d_in[12];

    unsigned char* ws = (unsigned char*)d_ws;
    int* deg    = (int*)(ws);                                // 200,704
    int* csum   = (int*)(ws + 200704);                       // 256
    float* scal = (float*)(ws + 200960);                     // 64
    int* start  = (int*)(ws + 201024);                       // 200,704
    int* cursor = (int*)(ws + 401728);                       // 200,704
    int* esrc   = (int*)(ws + 602432);                       // 3,200,000
    unsigned short* h1b = (unsigned short*)(ws + 3802432);   // 6,406,144
    unsigned short* Pd  = (unsigned short*)(ws + 10208576);  // 12,812,288
    unsigned char*  Ps  = (unsigned char*)(ws + 23020864);   // 6,406,144 (fp8)
    unsigned short* agg = (unsigned short*)(ws + 29427008);  // 6,406,144
    unsigned short* wt  = (unsigned short*)(ws + 35833152);  // 65,536

    hipMemsetAsync(d_ws, 0, 201024, stream);  // deg + csum + scal

    k_deg_prep<<<3125, 256, 0, stream>>>(ei, deg, Wf1, Ws1, Wf2, Ws2, wt);
    k_scan1<<<49, 1024, 0, stream>>>(deg, start, csum);
    k_scan23<<<49, 1024, 0, stream>>>(start, csum, cursor);
    k_fill<<<3125, 256, 0, stream>>>(ei, cursor, esrc);

    k_proj<0><<<NTILE, 256, 0, stream>>>(x, agg, h1b, wt, bf1, bs1, Pd, Ps);
    k_glean<<<2048, 256, 0, stream>>>((const unsigned int*)Pd, (const unsigned short*)Ps,
                                      esrc, start, agg);
    k_proj<1><<<NTILE, 256, 0, stream>>>(x, agg, h1b, wt + 16384, bf2, bs2, Pd, Ps);
    k_glean<<<2048, 256, 0, stream>>>((const unsigned int*)Pd, (const unsigned short*)Ps,
                                      esrc, start, agg);
    k_post2<<<512, 256, 0, stream>>>(h1b, agg, surf, Wlin, scal);
    k_final<<<1, 1, 0, stream>>>(scal, blin, (float*)d_out);
}